// Round 1
// baseline (5264.956 us; speedup 1.0000x reference)
//
#include <hip/hip_runtime.h>

#define HID 14

// ---------------- Edge pass ----------------
// For each edge e: mn = <x[row],x[row]>_M ; h = MLP1([mn, edge_attr[e]]) ;
// atomically accumulate h into seg[col] and 1.0 into cnt[col].
__global__ __launch_bounds__(256) void edge_kernel(
    const float* __restrict__ x,
    const int*   __restrict__ ei,     // [2,E] int32
    const float* __restrict__ ea,     // [E,14]
    const float* __restrict__ w1a, const float* __restrict__ b1a,
    const float* __restrict__ w1b, const float* __restrict__ b1b,
    float* __restrict__ seg,          // [N,14] accumulators
    float* __restrict__ cnt,          // [N] float counts
    int E)
{
    __shared__ float s_w1a[15 * HID];
    __shared__ float s_b1a[HID];
    __shared__ float s_w1b[HID * HID];
    __shared__ float s_b1b[HID];
    for (int i = threadIdx.x; i < 15 * HID; i += 256) s_w1a[i] = w1a[i];
    for (int i = threadIdx.x; i < HID * HID; i += 256) s_w1b[i] = w1b[i];
    if (threadIdx.x < HID) {
        s_b1a[threadIdx.x] = b1a[threadIdx.x];
        s_b1b[threadIdx.x] = b1b[threadIdx.x];
    }
    __syncthreads();

    int e = blockIdx.x * 256 + threadIdx.x;
    if (e >= E) return;

    int r = ei[e];
    int c = ei[E + e];

    float4 xv = ((const float4*)x)[r];                 // L2-resident gather
    float mn = xv.y * xv.y + xv.z * xv.z + xv.w * xv.w - xv.x * xv.x;

    // edge_attr[e]: 14 floats, base e*56 B is 8B-aligned -> 7x float2
    float v[HID];
    const float2* ep = (const float2*)(ea + (size_t)e * HID);
#pragma unroll
    for (int k = 0; k < 7; ++k) {
        float2 t = ep[k];
        v[2 * k] = t.x;
        v[2 * k + 1] = t.y;
    }

    float h1[HID];
#pragma unroll
    for (int j = 0; j < HID; ++j) h1[j] = s_b1a[j] + mn * s_w1a[j];
#pragma unroll
    for (int k = 0; k < HID; ++k) {
        float vk = v[k];
#pragma unroll
        for (int j = 0; j < HID; ++j) h1[j] += vk * s_w1a[(k + 1) * HID + j];
    }
#pragma unroll
    for (int j = 0; j < HID; ++j) h1[j] = fmaxf(h1[j], 0.0f);

    float h2[HID];
#pragma unroll
    for (int j = 0; j < HID; ++j) h2[j] = s_b1b[j];
#pragma unroll
    for (int k = 0; k < HID; ++k) {
        float hk = h1[k];
#pragma unroll
        for (int j = 0; j < HID; ++j) h2[j] += hk * s_w1b[k * HID + j];
    }

    float* dst = seg + (size_t)c * HID;
#pragma unroll
    for (int j = 0; j < HID; ++j) unsafeAtomicAdd(dst + j, h2[j]);
    unsafeAtomicAdd(cnt + c, 1.0f);
}

// ---------------- Node pass ----------------
__global__ __launch_bounds__(256) void node_kernel(
    const float* __restrict__ x,
    const float* __restrict__ seg,
    const float* __restrict__ cnt,
    const float* __restrict__ w2a, const float* __restrict__ b2a,
    const float* __restrict__ w2b, const float* __restrict__ b2b,
    float* __restrict__ out,
    int N)
{
    __shared__ float s_w2a[15 * HID];
    __shared__ float s_b2a[HID];
    __shared__ float s_w2b[HID * HID];
    __shared__ float s_b2b[HID];
    for (int i = threadIdx.x; i < 15 * HID; i += 256) s_w2a[i] = w2a[i];
    for (int i = threadIdx.x; i < HID * HID; i += 256) s_w2b[i] = w2b[i];
    if (threadIdx.x < HID) {
        s_b2a[threadIdx.x] = b2a[threadIdx.x];
        s_b2b[threadIdx.x] = b2b[threadIdx.x];
    }
    __syncthreads();

    int n = blockIdx.x * 256 + threadIdx.x;
    if (n >= N) return;

    float4 xv = ((const float4*)x)[n];
    float mn = xv.y * xv.y + xv.z * xv.z + xv.w * xv.w - xv.x * xv.x;

    float inv = 1.0f / fmaxf(cnt[n], 1.0f);

    float v[HID];
    const float2* sp = (const float2*)(seg + (size_t)n * HID);
#pragma unroll
    for (int k = 0; k < 7; ++k) {
        float2 t = sp[k];
        v[2 * k] = t.x * inv;
        v[2 * k + 1] = t.y * inv;
    }

    float h1[HID];
#pragma unroll
    for (int j = 0; j < HID; ++j) h1[j] = s_b2a[j] + mn * s_w2a[j];
#pragma unroll
    for (int k = 0; k < HID; ++k) {
        float vk = v[k];
#pragma unroll
        for (int j = 0; j < HID; ++j) h1[j] += vk * s_w2a[(k + 1) * HID + j];
    }
#pragma unroll
    for (int j = 0; j < HID; ++j) h1[j] = fmaxf(h1[j], 0.0f);

    float h2[HID];
#pragma unroll
    for (int j = 0; j < HID; ++j) h2[j] = s_b2b[j];
#pragma unroll
    for (int k = 0; k < HID; ++k) {
        float hk = h1[k];
#pragma unroll
        for (int j = 0; j < HID; ++j) h2[j] += hk * s_w2b[k * HID + j];
    }

    float2* op = (float2*)(out + (size_t)n * HID);
#pragma unroll
    for (int k = 0; k < 7; ++k) {
        float2 t;
        t.x = h2[2 * k];
        t.y = h2[2 * k + 1];
        op[k] = t;
    }
}

extern "C" void kernel_launch(void* const* d_in, const int* in_sizes, int n_in,
                              void* d_out, int out_size, void* d_ws, size_t ws_size,
                              hipStream_t stream)
{
    const float* x   = (const float*)d_in[0];
    const int*   ei  = (const int*)d_in[1];
    const float* ea  = (const float*)d_in[2];
    // d_in[3] = u, d_in[4] = batch : unused (single graph, batch all zeros)
    const float* w1a = (const float*)d_in[5];
    const float* b1a = (const float*)d_in[6];
    const float* w1b = (const float*)d_in[7];
    const float* b1b = (const float*)d_in[8];
    const float* w2a = (const float*)d_in[9];
    const float* b2a = (const float*)d_in[10];
    const float* w2b = (const float*)d_in[11];
    const float* b2b = (const float*)d_in[12];

    const int N = in_sizes[0] / 4;       // 100000
    const int E = in_sizes[1] / 2;       // 6400000

    float* seg = (float*)d_ws;           // N*14 floats
    float* cnt = seg + (size_t)N * HID;  // N floats

    hipMemsetAsync(d_ws, 0, (size_t)N * (HID + 1) * sizeof(float), stream);

    int eb = (E + 255) / 256;
    edge_kernel<<<eb, 256, 0, stream>>>(x, ei, ea, w1a, b1a, w1b, b1b, seg, cnt, E);

    int nb = (N + 255) / 256;
    node_kernel<<<nb, 256, 0, stream>>>(x, seg, cnt, w2a, b2a, w2b, b2b,
                                        (float*)d_out, N);
}

// Round 2
// 1490.278 us; speedup vs baseline: 3.5329x; 3.5329x over previous
//
#include <hip/hip_runtime.h>

#define HID 14
#define RNODE 256      // nodes per bucket (LDS accumulator range)
#define MSLICE 2       // parallel slices per bucket (merged in node pass)
#define MAXK 512       // max buckets supported by LDS arrays
#define PTILE 2048     // edges per partition block (256 thr x 8)

// ============ Fast path ============

// K1: histogram of destination buckets
__global__ __launch_bounds__(256) void hist_kernel(
    const int* __restrict__ col, int E, int* __restrict__ hist, int K)
{
    __shared__ int sh[MAXK];
    for (int i = threadIdx.x; i < K; i += 256) sh[i] = 0;
    __syncthreads();
    for (int i = blockIdx.x * 256 + threadIdx.x; i < E; i += gridDim.x * 256)
        atomicAdd(&sh[col[i] >> 8], 1);
    __syncthreads();
    for (int i = threadIdx.x; i < K; i += 256)
        if (sh[i]) atomicAdd(&hist[i], sh[i]);
}

// K2: serial exclusive scan (K ~ 391, negligible)
__global__ void scan_kernel(const int* __restrict__ hist,
                            int* __restrict__ start, int* __restrict__ cursor, int K)
{
    int acc = 0;
    for (int b = 0; b < K; ++b) {
        start[b] = acc;
        cursor[b] = acc;
        acc += hist[b];
    }
}

// K3: partition edges into buckets; payload = {edge_id, row, col, 0}
__global__ __launch_bounds__(256) void part_kernel(
    const int* __restrict__ ei, int E,
    int* __restrict__ cursor, int4* __restrict__ bins, int K)
{
    __shared__ int sh[MAXK];
    __shared__ int sbase[MAXK];
    for (int i = threadIdx.x; i < K; i += 256) sh[i] = 0;
    __syncthreads();

    int tile0 = blockIdx.x * PTILE;
    int e[8], r[8], c[8], rk[8];
#pragma unroll
    for (int k = 0; k < 8; ++k) {
        int idx = tile0 + k * 256 + threadIdx.x;
        e[k] = idx;
        if (idx < E) {
            r[k] = ei[idx];
            c[k] = ei[E + idx];
            rk[k] = atomicAdd(&sh[c[k] >> 8], 1);
        }
    }
    __syncthreads();
    for (int i = threadIdx.x; i < K; i += 256)
        sbase[i] = sh[i] ? atomicAdd(&cursor[i], sh[i]) : 0;
    __syncthreads();
#pragma unroll
    for (int k = 0; k < 8; ++k) {
        if (e[k] < E) {
            int pos = sbase[c[k] >> 8] + rk[k];
            int4 t; t.x = e[k]; t.y = r[k]; t.z = c[k]; t.w = 0;
            bins[pos] = t;
        }
    }
}

// K4: per-bucket-slice MLP1 + LDS accumulation (sums + count)
__global__ __launch_bounds__(256) void acc_kernel(
    const float* __restrict__ x,
    const float* __restrict__ ea,
    const int4* __restrict__ bins,
    const int* __restrict__ start, const int* __restrict__ hist,
    const float* __restrict__ w1a, const float* __restrict__ b1a,
    const float* __restrict__ w1b, const float* __restrict__ b1b,
    float* __restrict__ part, int N)
{
    __shared__ float sacc[RNODE * 15];
    __shared__ float s_w1a[15 * HID];
    __shared__ float s_b1a[HID];
    __shared__ float s_w1b[HID * HID];
    __shared__ float s_b1b[HID];
    for (int i = threadIdx.x; i < 15 * HID; i += 256) s_w1a[i] = w1a[i];
    for (int i = threadIdx.x; i < HID * HID; i += 256) s_w1b[i] = w1b[i];
    if (threadIdx.x < HID) {
        s_b1a[threadIdx.x] = b1a[threadIdx.x];
        s_b1b[threadIdx.x] = b1b[threadIdx.x];
    }
    for (int i = threadIdx.x; i < RNODE * 15; i += 256) sacc[i] = 0.0f;
    __syncthreads();

    int b = blockIdx.x / MSLICE;
    int m = blockIdx.x % MSLICE;
    int s0 = start[b];
    int cb = hist[b];
    int lo = s0 + (int)((long long)cb * m / MSLICE);
    int hi = s0 + (int)((long long)cb * (m + 1) / MSLICE);
    int nbase = b << 8;

    for (int i = lo + threadIdx.x; i < hi; i += 256) {
        int4 t = bins[i];

        float4 xv = ((const float4*)x)[t.y];
        float mn = xv.y * xv.y + xv.z * xv.z + xv.w * xv.w - xv.x * xv.x;

        float v[HID];
        const float2* ep = (const float2*)(ea + (size_t)t.x * HID);
#pragma unroll
        for (int k = 0; k < 7; ++k) {
            float2 u2 = ep[k];
            v[2 * k] = u2.x;
            v[2 * k + 1] = u2.y;
        }

        float h1[HID];
#pragma unroll
        for (int j = 0; j < HID; ++j) h1[j] = s_b1a[j] + mn * s_w1a[j];
#pragma unroll
        for (int k = 0; k < HID; ++k) {
            float vk = v[k];
#pragma unroll
            for (int j = 0; j < HID; ++j) h1[j] += vk * s_w1a[(k + 1) * HID + j];
        }
#pragma unroll
        for (int j = 0; j < HID; ++j) h1[j] = fmaxf(h1[j], 0.0f);

        float h2[HID];
#pragma unroll
        for (int j = 0; j < HID; ++j) h2[j] = s_b1b[j];
#pragma unroll
        for (int k = 0; k < HID; ++k) {
            float hk = h1[k];
#pragma unroll
            for (int j = 0; j < HID; ++j) h2[j] += hk * s_w1b[k * HID + j];
        }

        float* dst = &sacc[(t.z - nbase) * 15];
#pragma unroll
        for (int j = 0; j < HID; ++j) atomicAdd(dst + j, h2[j]);
        atomicAdd(dst + HID, 1.0f);
    }
    __syncthreads();

    // write this slice's partials
    for (int i = threadIdx.x; i < RNODE * 15; i += 256) {
        int node = nbase + i / 15;
        if (node < N)
            part[((size_t)m * N + node) * 15 + (i % 15)] = sacc[i];
    }
}

// K5: merge partials, mean, MLP2 -> out
__global__ __launch_bounds__(256) void node2_kernel(
    const float* __restrict__ x,
    const float* __restrict__ part,
    const float* __restrict__ w2a, const float* __restrict__ b2a,
    const float* __restrict__ w2b, const float* __restrict__ b2b,
    float* __restrict__ out, int N)
{
    __shared__ float s_w2a[15 * HID];
    __shared__ float s_b2a[HID];
    __shared__ float s_w2b[HID * HID];
    __shared__ float s_b2b[HID];
    for (int i = threadIdx.x; i < 15 * HID; i += 256) s_w2a[i] = w2a[i];
    for (int i = threadIdx.x; i < HID * HID; i += 256) s_w2b[i] = w2b[i];
    if (threadIdx.x < HID) {
        s_b2a[threadIdx.x] = b2a[threadIdx.x];
        s_b2b[threadIdx.x] = b2b[threadIdx.x];
    }
    __syncthreads();

    int n = blockIdx.x * 256 + threadIdx.x;
    if (n >= N) return;

    float4 xv = ((const float4*)x)[n];
    float mn = xv.y * xv.y + xv.z * xv.z + xv.w * xv.w - xv.x * xv.x;

    float s[15];
#pragma unroll
    for (int j = 0; j < 15; ++j)
        s[j] = part[(size_t)n * 15 + j] + part[((size_t)N + n) * 15 + j];

    float inv = 1.0f / fmaxf(s[HID], 1.0f);

    float h1[HID];
#pragma unroll
    for (int j = 0; j < HID; ++j) h1[j] = s_b2a[j] + mn * s_w2a[j];
#pragma unroll
    for (int k = 0; k < HID; ++k) {
        float vk = s[k] * inv;
#pragma unroll
        for (int j = 0; j < HID; ++j) h1[j] += vk * s_w2a[(k + 1) * HID + j];
    }
#pragma unroll
    for (int j = 0; j < HID; ++j) h1[j] = fmaxf(h1[j], 0.0f);

    float h2[HID];
#pragma unroll
    for (int j = 0; j < HID; ++j) h2[j] = s_b2b[j];
#pragma unroll
    for (int k = 0; k < HID; ++k) {
        float hk = h1[k];
#pragma unroll
        for (int j = 0; j < HID; ++j) h2[j] += hk * s_w2b[k * HID + j];
    }

    float2* op = (float2*)(out + (size_t)n * HID);
#pragma unroll
    for (int k = 0; k < 7; ++k) {
        float2 t;
        t.x = h2[2 * k];
        t.y = h2[2 * k + 1];
        op[k] = t;
    }
}

// ============ Fallback path (round-1, global atomics) ============

__global__ __launch_bounds__(256) void edge_kernel(
    const float* __restrict__ x, const int* __restrict__ ei,
    const float* __restrict__ ea,
    const float* __restrict__ w1a, const float* __restrict__ b1a,
    const float* __restrict__ w1b, const float* __restrict__ b1b,
    float* __restrict__ seg, float* __restrict__ cnt, int E)
{
    __shared__ float s_w1a[15 * HID];
    __shared__ float s_b1a[HID];
    __shared__ float s_w1b[HID * HID];
    __shared__ float s_b1b[HID];
    for (int i = threadIdx.x; i < 15 * HID; i += 256) s_w1a[i] = w1a[i];
    for (int i = threadIdx.x; i < HID * HID; i += 256) s_w1b[i] = w1b[i];
    if (threadIdx.x < HID) {
        s_b1a[threadIdx.x] = b1a[threadIdx.x];
        s_b1b[threadIdx.x] = b1b[threadIdx.x];
    }
    __syncthreads();

    int e = blockIdx.x * 256 + threadIdx.x;
    if (e >= E) return;
    int r = ei[e];
    int c = ei[E + e];
    float4 xv = ((const float4*)x)[r];
    float mn = xv.y * xv.y + xv.z * xv.z + xv.w * xv.w - xv.x * xv.x;
    float v[HID];
    const float2* ep = (const float2*)(ea + (size_t)e * HID);
#pragma unroll
    for (int k = 0; k < 7; ++k) { float2 t = ep[k]; v[2*k] = t.x; v[2*k+1] = t.y; }
    float h1[HID];
#pragma unroll
    for (int j = 0; j < HID; ++j) h1[j] = s_b1a[j] + mn * s_w1a[j];
#pragma unroll
    for (int k = 0; k < HID; ++k) {
        float vk = v[k];
#pragma unroll
        for (int j = 0; j < HID; ++j) h1[j] += vk * s_w1a[(k + 1) * HID + j];
    }
#pragma unroll
    for (int j = 0; j < HID; ++j) h1[j] = fmaxf(h1[j], 0.0f);
    float h2[HID];
#pragma unroll
    for (int j = 0; j < HID; ++j) h2[j] = s_b1b[j];
#pragma unroll
    for (int k = 0; k < HID; ++k) {
        float hk = h1[k];
#pragma unroll
        for (int j = 0; j < HID; ++j) h2[j] += hk * s_w1b[k * HID + j];
    }
    float* dst = seg + (size_t)c * HID;
#pragma unroll
    for (int j = 0; j < HID; ++j) unsafeAtomicAdd(dst + j, h2[j]);
    unsafeAtomicAdd(cnt + c, 1.0f);
}

__global__ __launch_bounds__(256) void node_kernel(
    const float* __restrict__ x, const float* __restrict__ seg,
    const float* __restrict__ cnt,
    const float* __restrict__ w2a, const float* __restrict__ b2a,
    const float* __restrict__ w2b, const float* __restrict__ b2b,
    float* __restrict__ out, int N)
{
    __shared__ float s_w2a[15 * HID];
    __shared__ float s_b2a[HID];
    __shared__ float s_w2b[HID * HID];
    __shared__ float s_b2b[HID];
    for (int i = threadIdx.x; i < 15 * HID; i += 256) s_w2a[i] = w2a[i];
    for (int i = threadIdx.x; i < HID * HID; i += 256) s_w2b[i] = w2b[i];
    if (threadIdx.x < HID) {
        s_b2a[threadIdx.x] = b2a[threadIdx.x];
        s_b2b[threadIdx.x] = b2b[threadIdx.x];
    }
    __syncthreads();
    int n = blockIdx.x * 256 + threadIdx.x;
    if (n >= N) return;
    float4 xv = ((const float4*)x)[n];
    float mn = xv.y * xv.y + xv.z * xv.z + xv.w * xv.w - xv.x * xv.x;
    float inv = 1.0f / fmaxf(cnt[n], 1.0f);
    float v[HID];
    const float2* sp = (const float2*)(seg + (size_t)n * HID);
#pragma unroll
    for (int k = 0; k < 7; ++k) { float2 t = sp[k]; v[2*k] = t.x*inv; v[2*k+1] = t.y*inv; }
    float h1[HID];
#pragma unroll
    for (int j = 0; j < HID; ++j) h1[j] = s_b2a[j] + mn * s_w2a[j];
#pragma unroll
    for (int k = 0; k < HID; ++k) {
        float vk = v[k];
#pragma unroll
        for (int j = 0; j < HID; ++j) h1[j] += vk * s_w2a[(k + 1) * HID + j];
    }
#pragma unroll
    for (int j = 0; j < HID; ++j) h1[j] = fmaxf(h1[j], 0.0f);
    float h2[HID];
#pragma unroll
    for (int j = 0; j < HID; ++j) h2[j] = s_b2b[j];
#pragma unroll
    for (int k = 0; k < HID; ++k) {
        float hk = h1[k];
#pragma unroll
        for (int j = 0; j < HID; ++j) h2[j] += hk * s_w2b[k * HID + j];
    }
    float2* op = (float2*)(out + (size_t)n * HID);
#pragma unroll
    for (int k = 0; k < 7; ++k) { float2 t; t.x = h2[2*k]; t.y = h2[2*k+1]; op[k] = t; }
}

// ============ Launch ============

extern "C" void kernel_launch(void* const* d_in, const int* in_sizes, int n_in,
                              void* d_out, int out_size, void* d_ws, size_t ws_size,
                              hipStream_t stream)
{
    const float* x   = (const float*)d_in[0];
    const int*   ei  = (const int*)d_in[1];
    const float* ea  = (const float*)d_in[2];
    const float* w1a = (const float*)d_in[5];
    const float* b1a = (const float*)d_in[6];
    const float* w1b = (const float*)d_in[7];
    const float* b1b = (const float*)d_in[8];
    const float* w2a = (const float*)d_in[9];
    const float* b2a = (const float*)d_in[10];
    const float* w2b = (const float*)d_in[11];
    const float* b2b = (const float*)d_in[12];

    const int N = in_sizes[0] / 4;   // 100000
    const int E = in_sizes[1] / 2;   // 6400000
    const int K = (N + RNODE - 1) / RNODE;

    // fast-path workspace layout
    size_t bins_bytes = (size_t)E * sizeof(int4);
    size_t part_bytes = (size_t)MSLICE * N * 15 * sizeof(float);
    size_t ints_bytes = (size_t)3 * K * sizeof(int);
    size_t need = bins_bytes + part_bytes + ints_bytes + 256;

    if (K <= MAXK && ws_size >= need) {
        int4*  bins   = (int4*)d_ws;
        float* part   = (float*)((char*)d_ws + bins_bytes);
        int*   hist   = (int*)((char*)d_ws + bins_bytes + part_bytes);
        int*   cursor = hist + K;
        int*   start  = cursor + K;

        hipMemsetAsync(hist, 0, 2 * (size_t)K * sizeof(int), stream);

        hist_kernel<<<1024, 256, 0, stream>>>(ei + E, E, hist, K);
        scan_kernel<<<1, 1, 0, stream>>>(hist, start, cursor, K);
        int pb = (E + PTILE - 1) / PTILE;
        part_kernel<<<pb, 256, 0, stream>>>(ei, E, cursor, bins, K);
        acc_kernel<<<K * MSLICE, 256, 0, stream>>>(x, ea, bins, start, hist,
                                                   w1a, b1a, w1b, b1b, part, N);
        int nb = (N + 255) / 256;
        node2_kernel<<<nb, 256, 0, stream>>>(x, part, w2a, b2a, w2b, b2b,
                                             (float*)d_out, N);
    } else {
        // fallback: round-1 atomic path
        float* seg = (float*)d_ws;
        float* cnt = seg + (size_t)N * HID;
        hipMemsetAsync(d_ws, 0, (size_t)N * (HID + 1) * sizeof(float), stream);
        int eb = (E + 255) / 256;
        edge_kernel<<<eb, 256, 0, stream>>>(x, ei, ea, w1a, b1a, w1b, b1b, seg, cnt, E);
        int nb = (N + 255) / 256;
        node_kernel<<<nb, 256, 0, stream>>>(x, seg, cnt, w2a, b2a, w2b, b2b,
                                            (float*)d_out, N);
    }
}

// Round 3
// 1325.904 us; speedup vs baseline: 3.9708x; 1.1240x over previous
//
#include <hip/hip_runtime.h>
#include <hip/hip_fp16.h>

#define HID 14
#define RNODE 256      // nodes per bucket
#define MSLICE 4       // acc slices per bucket (fast path)
#define MAXK 512
#define PTILE 2048     // edges per partition block

static __device__ inline unsigned pack2(float a, float b) {
    return __builtin_bit_cast(unsigned, __floats2half2_rn(a, b));
}
static __device__ inline float2 unpack2(unsigned u) {
    return __half22float2(__builtin_bit_cast(__half2, u));
}

// ============ Shared infra: hist + scan ============

__global__ __launch_bounds__(256) void hist_kernel(
    const int* __restrict__ col, int E, int* __restrict__ hist, int K)
{
    __shared__ int sh[MAXK];
    for (int i = threadIdx.x; i < K; i += 256) sh[i] = 0;
    __syncthreads();
    for (int i = blockIdx.x * 256 + threadIdx.x; i < E; i += gridDim.x * 256)
        atomicAdd(&sh[col[i] >> 8], 1);
    __syncthreads();
    for (int i = threadIdx.x; i < K; i += 256)
        if (sh[i]) atomicAdd(&hist[i], sh[i]);
}

// parallel block scan (K <= 512), replaces slow serial scan
__global__ __launch_bounds__(512) void scan_kernel(
    const int* __restrict__ hist,
    int* __restrict__ start, int* __restrict__ cursor, int K)
{
    __shared__ int s[512];
    int t = threadIdx.x;
    int v = (t < K) ? hist[t] : 0;
    s[t] = v;
    __syncthreads();
    for (int off = 1; off < 512; off <<= 1) {
        int add = (t >= off) ? s[t - off] : 0;
        __syncthreads();
        s[t] += add;
        __syncthreads();
    }
    if (t < K) {
        int ex = s[t] - v;   // exclusive
        start[t] = ex;
        cursor[t] = ex;
    }
}

// ============ Fast path ============

// K3: partition + MLP1 fused. Streams ei+ea coalesced; writes 32B records
// {r0..r13 as fp16, col} to binned position (scattered writes = latency-tolerant).
__global__ __launch_bounds__(256) void part_kernel(
    const float* __restrict__ x,
    const int* __restrict__ ei, int E,
    const float* __restrict__ ea,
    const float* __restrict__ w1a, const float* __restrict__ b1a,
    int* __restrict__ cursor, uint4* __restrict__ recs, int K)
{
    __shared__ int sh[MAXK];
    __shared__ int sbase[MAXK];
    __shared__ float s_w1a[15 * HID];
    __shared__ float s_b1a[HID];
    for (int i = threadIdx.x; i < 15 * HID; i += 256) s_w1a[i] = w1a[i];
    if (threadIdx.x < HID) s_b1a[threadIdx.x] = b1a[threadIdx.x];
    for (int i = threadIdx.x; i < K; i += 256) sh[i] = 0;
    __syncthreads();

    int tile0 = blockIdx.x * PTILE;
    int r[8], c[8], rk[8];
#pragma unroll
    for (int k = 0; k < 8; ++k) {
        int idx = tile0 + k * 256 + threadIdx.x;
        if (idx < E) {
            r[k] = ei[idx];
            c[k] = ei[E + idx];
            rk[k] = atomicAdd(&sh[c[k] >> 8], 1);
        }
    }
    __syncthreads();
    for (int i = threadIdx.x; i < K; i += 256)
        sbase[i] = sh[i] ? atomicAdd(&cursor[i], sh[i]) : 0;
    __syncthreads();

#pragma unroll
    for (int k = 0; k < 8; ++k) {
        int idx = tile0 + k * 256 + threadIdx.x;
        if (idx < E) {
            float4 xv = ((const float4*)x)[r[k]];
            float mn = xv.y * xv.y + xv.z * xv.z + xv.w * xv.w - xv.x * xv.x;

            float v[HID];
            const float2* ep = (const float2*)(ea + (size_t)idx * HID);
#pragma unroll
            for (int q = 0; q < 7; ++q) {
                float2 t = ep[q];
                v[2 * q] = t.x;
                v[2 * q + 1] = t.y;
            }

            float h1[HID];
#pragma unroll
            for (int j = 0; j < HID; ++j) h1[j] = s_b1a[j] + mn * s_w1a[j];
#pragma unroll
            for (int q = 0; q < HID; ++q) {
                float vq = v[q];
#pragma unroll
                for (int j = 0; j < HID; ++j) h1[j] += vq * s_w1a[(q + 1) * HID + j];
            }
#pragma unroll
            for (int j = 0; j < HID; ++j) h1[j] = fmaxf(h1[j], 0.0f);

            size_t pos = (size_t)(sbase[c[k] >> 8] + rk[k]);
            uint4 ua, ub;
            ua.x = pack2(h1[0], h1[1]);   ua.y = pack2(h1[2], h1[3]);
            ua.z = pack2(h1[4], h1[5]);   ua.w = pack2(h1[6], h1[7]);
            ub.x = pack2(h1[8], h1[9]);   ub.y = pack2(h1[10], h1[11]);
            ub.z = pack2(h1[12], h1[13]); ub.w = (unsigned)c[k];
            recs[2 * pos]     = ua;
            recs[2 * pos + 1] = ub;
        }
    }
}

// K4: pure streaming accumulate: sequential record reads + LDS atomics.
__global__ __launch_bounds__(256) void acc_kernel(
    const uint4* __restrict__ recs,
    const int* __restrict__ start, const int* __restrict__ hist,
    float* __restrict__ part, int N)
{
    __shared__ float sacc[RNODE * 15];   // stride 15 (odd) -> good bank spread
    for (int i = threadIdx.x; i < RNODE * 15; i += 256) sacc[i] = 0.0f;
    __syncthreads();

    int b = blockIdx.x / MSLICE;
    int m = blockIdx.x % MSLICE;
    int s0 = start[b], cb = hist[b];
    int lo = s0 + (int)((long long)cb * m / MSLICE);
    int hi = s0 + (int)((long long)cb * (m + 1) / MSLICE);
    int nbase = b << 8;

    for (int i = lo + threadIdx.x; i < hi; i += 256) {
        uint4 ua = recs[2 * (size_t)i];
        uint4 ub = recs[2 * (size_t)i + 1];
        float* dst = &sacc[((int)ub.w - nbase) * 15];
        float2 f;
        f = unpack2(ua.x); atomicAdd(dst + 0,  f.x); atomicAdd(dst + 1,  f.y);
        f = unpack2(ua.y); atomicAdd(dst + 2,  f.x); atomicAdd(dst + 3,  f.y);
        f = unpack2(ua.z); atomicAdd(dst + 4,  f.x); atomicAdd(dst + 5,  f.y);
        f = unpack2(ua.w); atomicAdd(dst + 6,  f.x); atomicAdd(dst + 7,  f.y);
        f = unpack2(ub.x); atomicAdd(dst + 8,  f.x); atomicAdd(dst + 9,  f.y);
        f = unpack2(ub.y); atomicAdd(dst + 10, f.x); atomicAdd(dst + 11, f.y);
        f = unpack2(ub.z); atomicAdd(dst + 12, f.x); atomicAdd(dst + 13, f.y);
        atomicAdd(dst + 14, 1.0f);
    }
    __syncthreads();

    for (int i = threadIdx.x; i < RNODE * 15; i += 256) {
        int node = nbase + i / 15;
        if (node < N)
            part[((size_t)m * N + node) * 16 + (i % 15)] = sacc[i];
    }
}

// K5: merge partials, mean, fold W1b/b1b (linearity), MLP2 -> out
__global__ __launch_bounds__(256) void node2_kernel(
    const float* __restrict__ x,
    const float* __restrict__ part,
    const float* __restrict__ w1b, const float* __restrict__ b1b,
    const float* __restrict__ w2a, const float* __restrict__ b2a,
    const float* __restrict__ w2b, const float* __restrict__ b2b,
    float* __restrict__ out, int N)
{
    __shared__ float s_w1b[HID * HID], s_b1b[HID];
    __shared__ float s_w2a[15 * HID], s_b2a[HID];
    __shared__ float s_w2b[HID * HID], s_b2b[HID];
    for (int i = threadIdx.x; i < HID * HID; i += 256) {
        s_w1b[i] = w1b[i];
        s_w2b[i] = w2b[i];
    }
    for (int i = threadIdx.x; i < 15 * HID; i += 256) s_w2a[i] = w2a[i];
    if (threadIdx.x < HID) {
        s_b1b[threadIdx.x] = b1b[threadIdx.x];
        s_b2a[threadIdx.x] = b2a[threadIdx.x];
        s_b2b[threadIdx.x] = b2b[threadIdx.x];
    }
    __syncthreads();

    int n = blockIdx.x * 256 + threadIdx.x;
    if (n >= N) return;

    float s[15];
    {
        const float4* p = (const float4*)(part + (size_t)n * 16);
        float4 a = p[0], bq = p[1], cq = p[2], dq = p[3];
        s[0] = a.x;  s[1] = a.y;  s[2] = a.z;  s[3] = a.w;
        s[4] = bq.x; s[5] = bq.y; s[6] = bq.z; s[7] = bq.w;
        s[8] = cq.x; s[9] = cq.y; s[10] = cq.z; s[11] = cq.w;
        s[12] = dq.x; s[13] = dq.y; s[14] = dq.z;   // dq.w = pad, ignore
    }
#pragma unroll
    for (int m = 1; m < MSLICE; ++m) {
        const float4* p = (const float4*)(part + ((size_t)m * N + n) * 16);
        float4 a = p[0], bq = p[1], cq = p[2], dq = p[3];
        s[0] += a.x;  s[1] += a.y;  s[2] += a.z;  s[3] += a.w;
        s[4] += bq.x; s[5] += bq.y; s[6] += bq.z; s[7] += bq.w;
        s[8] += cq.x; s[9] += cq.y; s[10] += cq.z; s[11] += cq.w;
        s[12] += dq.x; s[13] += dq.y; s[14] += dq.z;
    }

    float cntf = s[14];
    float gate = (cntf >= 0.5f) ? 1.0f : 0.0f;      // ref: mean==0 if no edges
    float inv = gate / fmaxf(cntf, 1.0f);

    // mean(h2) = W1b . mean(relu_h1) + b1b   (gated)
    float mh[HID];
#pragma unroll
    for (int j = 0; j < HID; ++j) mh[j] = gate * s_b1b[j];
#pragma unroll
    for (int k = 0; k < HID; ++k) {
        float rk = s[k] * inv;
#pragma unroll
        for (int j = 0; j < HID; ++j) mh[j] += rk * s_w1b[k * HID + j];
    }

    float4 xv = ((const float4*)x)[n];
    float mn = xv.y * xv.y + xv.z * xv.z + xv.w * xv.w - xv.x * xv.x;

    float h1[HID];
#pragma unroll
    for (int j = 0; j < HID; ++j) h1[j] = s_b2a[j] + mn * s_w2a[j];
#pragma unroll
    for (int k = 0; k < HID; ++k) {
        float vk = mh[k];
#pragma unroll
        for (int j = 0; j < HID; ++j) h1[j] += vk * s_w2a[(k + 1) * HID + j];
    }
#pragma unroll
    for (int j = 0; j < HID; ++j) h1[j] = fmaxf(h1[j], 0.0f);

    float h2[HID];
#pragma unroll
    for (int j = 0; j < HID; ++j) h2[j] = s_b2b[j];
#pragma unroll
    for (int k = 0; k < HID; ++k) {
        float hk = h1[k];
#pragma unroll
        for (int j = 0; j < HID; ++j) h2[j] += hk * s_w2b[k * HID + j];
    }

    float2* op = (float2*)(out + (size_t)n * HID);
#pragma unroll
    for (int k = 0; k < 7; ++k) {
        float2 t; t.x = h2[2 * k]; t.y = h2[2 * k + 1];
        op[k] = t;
    }
}

// ============ Fallback A (round-2): edge-id bins + MLP in acc ============

__global__ __launch_bounds__(256) void r2_part_kernel(
    const int* __restrict__ ei, int E,
    int* __restrict__ cursor, int4* __restrict__ bins, int K)
{
    __shared__ int sh[MAXK];
    __shared__ int sbase[MAXK];
    for (int i = threadIdx.x; i < K; i += 256) sh[i] = 0;
    __syncthreads();
    int tile0 = blockIdx.x * PTILE;
    int e[8], r[8], c[8], rk[8];
#pragma unroll
    for (int k = 0; k < 8; ++k) {
        int idx = tile0 + k * 256 + threadIdx.x;
        e[k] = idx;
        if (idx < E) {
            r[k] = ei[idx];
            c[k] = ei[E + idx];
            rk[k] = atomicAdd(&sh[c[k] >> 8], 1);
        }
    }
    __syncthreads();
    for (int i = threadIdx.x; i < K; i += 256)
        sbase[i] = sh[i] ? atomicAdd(&cursor[i], sh[i]) : 0;
    __syncthreads();
#pragma unroll
    for (int k = 0; k < 8; ++k) {
        if (e[k] < E) {
            int pos = sbase[c[k] >> 8] + rk[k];
            int4 t; t.x = e[k]; t.y = r[k]; t.z = c[k]; t.w = 0;
            bins[pos] = t;
        }
    }
}

__global__ __launch_bounds__(256) void r2_acc_kernel(
    const float* __restrict__ x, const float* __restrict__ ea,
    const int4* __restrict__ bins,
    const int* __restrict__ start, const int* __restrict__ hist,
    const float* __restrict__ w1a, const float* __restrict__ b1a,
    const float* __restrict__ w1b, const float* __restrict__ b1b,
    float* __restrict__ part, int N)
{
    __shared__ float sacc[RNODE * 15];
    __shared__ float s_w1a[15 * HID], s_b1a[HID];
    __shared__ float s_w1b[HID * HID], s_b1b[HID];
    for (int i = threadIdx.x; i < 15 * HID; i += 256) s_w1a[i] = w1a[i];
    for (int i = threadIdx.x; i < HID * HID; i += 256) s_w1b[i] = w1b[i];
    if (threadIdx.x < HID) { s_b1a[threadIdx.x] = b1a[threadIdx.x]; s_b1b[threadIdx.x] = b1b[threadIdx.x]; }
    for (int i = threadIdx.x; i < RNODE * 15; i += 256) sacc[i] = 0.0f;
    __syncthreads();

    int b = blockIdx.x / 2, m = blockIdx.x % 2;
    int s0 = start[b], cb = hist[b];
    int lo = s0 + (int)((long long)cb * m / 2);
    int hi = s0 + (int)((long long)cb * (m + 1) / 2);
    int nbase = b << 8;

    for (int i = lo + threadIdx.x; i < hi; i += 256) {
        int4 t = bins[i];
        float4 xv = ((const float4*)x)[t.y];
        float mn = xv.y * xv.y + xv.z * xv.z + xv.w * xv.w - xv.x * xv.x;
        float v[HID];
        const float2* ep = (const float2*)(ea + (size_t)t.x * HID);
#pragma unroll
        for (int k = 0; k < 7; ++k) { float2 u2 = ep[k]; v[2*k] = u2.x; v[2*k+1] = u2.y; }
        float h1[HID];
#pragma unroll
        for (int j = 0; j < HID; ++j) h1[j] = s_b1a[j] + mn * s_w1a[j];
#pragma unroll
        for (int k = 0; k < HID; ++k) {
            float vk = v[k];
#pragma unroll
            for (int j = 0; j < HID; ++j) h1[j] += vk * s_w1a[(k + 1) * HID + j];
        }
#pragma unroll
        for (int j = 0; j < HID; ++j) h1[j] = fmaxf(h1[j], 0.0f);
        float h2[HID];
#pragma unroll
        for (int j = 0; j < HID; ++j) h2[j] = s_b1b[j];
#pragma unroll
        for (int k = 0; k < HID; ++k) {
            float hk = h1[k];
#pragma unroll
            for (int j = 0; j < HID; ++j) h2[j] += hk * s_w1b[k * HID + j];
        }
        float* dst = &sacc[(t.z - nbase) * 15];
#pragma unroll
        for (int j = 0; j < HID; ++j) atomicAdd(dst + j, h2[j]);
        atomicAdd(dst + HID, 1.0f);
    }
    __syncthreads();
    for (int i = threadIdx.x; i < RNODE * 15; i += 256) {
        int node = nbase + i / 15;
        if (node < N) part[((size_t)m * N + node) * 15 + (i % 15)] = sacc[i];
    }
}

__global__ __launch_bounds__(256) void r2_node2_kernel(
    const float* __restrict__ x, const float* __restrict__ part,
    const float* __restrict__ w2a, const float* __restrict__ b2a,
    const float* __restrict__ w2b, const float* __restrict__ b2b,
    float* __restrict__ out, int N)
{
    __shared__ float s_w2a[15 * HID], s_b2a[HID];
    __shared__ float s_w2b[HID * HID], s_b2b[HID];
    for (int i = threadIdx.x; i < 15 * HID; i += 256) s_w2a[i] = w2a[i];
    for (int i = threadIdx.x; i < HID * HID; i += 256) s_w2b[i] = w2b[i];
    if (threadIdx.x < HID) { s_b2a[threadIdx.x] = b2a[threadIdx.x]; s_b2b[threadIdx.x] = b2b[threadIdx.x]; }
    __syncthreads();
    int n = blockIdx.x * 256 + threadIdx.x;
    if (n >= N) return;
    float4 xv = ((const float4*)x)[n];
    float mn = xv.y * xv.y + xv.z * xv.z + xv.w * xv.w - xv.x * xv.x;
    float s[15];
#pragma unroll
    for (int j = 0; j < 15; ++j)
        s[j] = part[(size_t)n * 15 + j] + part[((size_t)N + n) * 15 + j];
    float inv = 1.0f / fmaxf(s[HID], 1.0f);
    float h1[HID];
#pragma unroll
    for (int j = 0; j < HID; ++j) h1[j] = s_b2a[j] + mn * s_w2a[j];
#pragma unroll
    for (int k = 0; k < HID; ++k) {
        float vk = s[k] * inv;
#pragma unroll
        for (int j = 0; j < HID; ++j) h1[j] += vk * s_w2a[(k + 1) * HID + j];
    }
#pragma unroll
    for (int j = 0; j < HID; ++j) h1[j] = fmaxf(h1[j], 0.0f);
    float h2[HID];
#pragma unroll
    for (int j = 0; j < HID; ++j) h2[j] = s_b2b[j];
#pragma unroll
    for (int k = 0; k < HID; ++k) {
        float hk = h1[k];
#pragma unroll
        for (int j = 0; j < HID; ++j) h2[j] += hk * s_w2b[k * HID + j];
    }
    float2* op = (float2*)(out + (size_t)n * HID);
#pragma unroll
    for (int k = 0; k < 7; ++k) { float2 t; t.x = h2[2*k]; t.y = h2[2*k+1]; op[k] = t; }
}

// ============ Fallback B (round-1): global atomics ============

__global__ __launch_bounds__(256) void edge_kernel(
    const float* __restrict__ x, const int* __restrict__ ei,
    const float* __restrict__ ea,
    const float* __restrict__ w1a, const float* __restrict__ b1a,
    const float* __restrict__ w1b, const float* __restrict__ b1b,
    float* __restrict__ seg, float* __restrict__ cnt, int E)
{
    __shared__ float s_w1a[15 * HID], s_b1a[HID];
    __shared__ float s_w1b[HID * HID], s_b1b[HID];
    for (int i = threadIdx.x; i < 15 * HID; i += 256) s_w1a[i] = w1a[i];
    for (int i = threadIdx.x; i < HID * HID; i += 256) s_w1b[i] = w1b[i];
    if (threadIdx.x < HID) { s_b1a[threadIdx.x] = b1a[threadIdx.x]; s_b1b[threadIdx.x] = b1b[threadIdx.x]; }
    __syncthreads();
    int e = blockIdx.x * 256 + threadIdx.x;
    if (e >= E) return;
    int r = ei[e], c = ei[E + e];
    float4 xv = ((const float4*)x)[r];
    float mn = xv.y * xv.y + xv.z * xv.z + xv.w * xv.w - xv.x * xv.x;
    float v[HID];
    const float2* ep = (const float2*)(ea + (size_t)e * HID);
#pragma unroll
    for (int k = 0; k < 7; ++k) { float2 t = ep[k]; v[2*k] = t.x; v[2*k+1] = t.y; }
    float h1[HID];
#pragma unroll
    for (int j = 0; j < HID; ++j) h1[j] = s_b1a[j] + mn * s_w1a[j];
#pragma unroll
    for (int k = 0; k < HID; ++k) {
        float vk = v[k];
#pragma unroll
        for (int j = 0; j < HID; ++j) h1[j] += vk * s_w1a[(k + 1) * HID + j];
    }
#pragma unroll
    for (int j = 0; j < HID; ++j) h1[j] = fmaxf(h1[j], 0.0f);
    float h2[HID];
#pragma unroll
    for (int j = 0; j < HID; ++j) h2[j] = s_b1b[j];
#pragma unroll
    for (int k = 0; k < HID; ++k) {
        float hk = h1[k];
#pragma unroll
        for (int j = 0; j < HID; ++j) h2[j] += hk * s_w1b[k * HID + j];
    }
    float* dst = seg + (size_t)c * HID;
#pragma unroll
    for (int j = 0; j < HID; ++j) unsafeAtomicAdd(dst + j, h2[j]);
    unsafeAtomicAdd(cnt + c, 1.0f);
}

__global__ __launch_bounds__(256) void node_kernel(
    const float* __restrict__ x, const float* __restrict__ seg,
    const float* __restrict__ cnt,
    const float* __restrict__ w2a, const float* __restrict__ b2a,
    const float* __restrict__ w2b, const float* __restrict__ b2b,
    float* __restrict__ out, int N)
{
    __shared__ float s_w2a[15 * HID], s_b2a[HID];
    __shared__ float s_w2b[HID * HID], s_b2b[HID];
    for (int i = threadIdx.x; i < 15 * HID; i += 256) s_w2a[i] = w2a[i];
    for (int i = threadIdx.x; i < HID * HID; i += 256) s_w2b[i] = w2b[i];
    if (threadIdx.x < HID) { s_b2a[threadIdx.x] = b2a[threadIdx.x]; s_b2b[threadIdx.x] = b2b[threadIdx.x]; }
    __syncthreads();
    int n = blockIdx.x * 256 + threadIdx.x;
    if (n >= N) return;
    float4 xv = ((const float4*)x)[n];
    float mn = xv.y * xv.y + xv.z * xv.z + xv.w * xv.w - xv.x * xv.x;
    float inv = 1.0f / fmaxf(cnt[n], 1.0f);
    float v[HID];
    const float2* sp = (const float2*)(seg + (size_t)n * HID);
#pragma unroll
    for (int k = 0; k < 7; ++k) { float2 t = sp[k]; v[2*k] = t.x*inv; v[2*k+1] = t.y*inv; }
    float h1[HID];
#pragma unroll
    for (int j = 0; j < HID; ++j) h1[j] = s_b2a[j] + mn * s_w2a[j];
#pragma unroll
    for (int k = 0; k < HID; ++k) {
        float vk = v[k];
#pragma unroll
        for (int j = 0; j < HID; ++j) h1[j] += vk * s_w2a[(k + 1) * HID + j];
    }
#pragma unroll
    for (int j = 0; j < HID; ++j) h1[j] = fmaxf(h1[j], 0.0f);
    float h2[HID];
#pragma unroll
    for (int j = 0; j < HID; ++j) h2[j] = s_b2b[j];
#pragma unroll
    for (int k = 0; k < HID; ++k) {
        float hk = h1[k];
#pragma unroll
        for (int j = 0; j < HID; ++j) h2[j] += hk * s_w2b[k * HID + j];
    }
    float2* op = (float2*)(out + (size_t)n * HID);
#pragma unroll
    for (int k = 0; k < 7; ++k) { float2 t; t.x = h2[2*k]; t.y = h2[2*k+1]; op[k] = t; }
}

// ============ Launch ============

extern "C" void kernel_launch(void* const* d_in, const int* in_sizes, int n_in,
                              void* d_out, int out_size, void* d_ws, size_t ws_size,
                              hipStream_t stream)
{
    const float* x   = (const float*)d_in[0];
    const int*   ei  = (const int*)d_in[1];
    const float* ea  = (const float*)d_in[2];
    const float* w1a = (const float*)d_in[5];
    const float* b1a = (const float*)d_in[6];
    const float* w1b = (const float*)d_in[7];
    const float* b1b = (const float*)d_in[8];
    const float* w2a = (const float*)d_in[9];
    const float* b2a = (const float*)d_in[10];
    const float* w2b = (const float*)d_in[11];
    const float* b2b = (const float*)d_in[12];

    const int N = in_sizes[0] / 4;   // 100000
    const int E = in_sizes[1] / 2;   // 6400000
    const int K = (N + RNODE - 1) / RNODE;

    size_t recs_bytes = (size_t)E * 32;
    size_t part_bytes = (size_t)MSLICE * N * 16 * sizeof(float);
    size_t ints_bytes = (size_t)3 * MAXK * sizeof(int);
    size_t need_fast = recs_bytes + part_bytes + ints_bytes + 256;

    size_t bins_bytes = (size_t)E * sizeof(int4);
    size_t r2part_bytes = (size_t)2 * N * 15 * sizeof(float);
    size_t need_r2 = bins_bytes + r2part_bytes + ints_bytes + 256;

    if (K <= MAXK && ws_size >= need_fast) {
        uint4* recs   = (uint4*)d_ws;
        float* part   = (float*)((char*)d_ws + recs_bytes);
        int*   hist   = (int*)((char*)d_ws + recs_bytes + part_bytes);
        int*   cursor = hist + MAXK;
        int*   start  = cursor + MAXK;

        hipMemsetAsync(hist, 0, (size_t)K * sizeof(int), stream);
        hist_kernel<<<1024, 256, 0, stream>>>(ei + E, E, hist, K);
        scan_kernel<<<1, 512, 0, stream>>>(hist, start, cursor, K);
        int pb = (E + PTILE - 1) / PTILE;
        part_kernel<<<pb, 256, 0, stream>>>(x, ei, E, ea, w1a, b1a, cursor, recs, K);
        acc_kernel<<<K * MSLICE, 256, 0, stream>>>(recs, start, hist, part, N);
        int nb = (N + 255) / 256;
        node2_kernel<<<nb, 256, 0, stream>>>(x, part, w1b, b1b, w2a, b2a, w2b, b2b,
                                             (float*)d_out, N);
    } else if (K <= MAXK && ws_size >= need_r2) {
        int4*  bins   = (int4*)d_ws;
        float* part   = (float*)((char*)d_ws + bins_bytes);
        int*   hist   = (int*)((char*)d_ws + bins_bytes + r2part_bytes);
        int*   cursor = hist + MAXK;
        int*   start  = cursor + MAXK;

        hipMemsetAsync(hist, 0, (size_t)K * sizeof(int), stream);
        hist_kernel<<<1024, 256, 0, stream>>>(ei + E, E, hist, K);
        scan_kernel<<<1, 512, 0, stream>>>(hist, start, cursor, K);
        int pb = (E + PTILE - 1) / PTILE;
        r2_part_kernel<<<pb, 256, 0, stream>>>(ei, E, cursor, bins, K);
        r2_acc_kernel<<<K * 2, 256, 0, stream>>>(x, ea, bins, start, hist,
                                                 w1a, b1a, w1b, b1b, part, N);
        int nb = (N + 255) / 256;
        r2_node2_kernel<<<nb, 256, 0, stream>>>(x, part, w2a, b2a, w2b, b2b,
                                                (float*)d_out, N);
    } else {
        float* seg = (float*)d_ws;
        float* cnt = seg + (size_t)N * HID;
        hipMemsetAsync(d_ws, 0, (size_t)N * (HID + 1) * sizeof(float), stream);
        int eb = (E + 255) / 256;
        edge_kernel<<<eb, 256, 0, stream>>>(x, ei, ea, w1a, b1a, w1b, b1b, seg, cnt, E);
        int nb = (N + 255) / 256;
        node_kernel<<<nb, 256, 0, stream>>>(x, seg, cnt, w2a, b2a, w2b, b2b,
                                            (float*)d_out, N);
    }
}